// Round 10
// baseline (174.925 us; speedup 1.0000x reference)
//
#include <hip/hip_runtime.h>

typedef float f32x4 __attribute__((ext_vector_type(4)));

#define POOLK 7
#define NBINS 49            // POOLK*POOLK
#define ALPHA 32
#define C4N   8             // ALPHA/4
#define HH    128
#define WW    128
#define NUM_ROIS 4096
#define F4_PER_PIX (NBINS * C4N)   // 392 float4 per (y,x) pixel
#define NXCD 8
#define SLOTS_PER_XCD 784          // 6272 / 8
#define CHUNKS_PER_PLANE 128

// ---------------------------------------------------------------------------
// Pass 1: spatial bucket-sort of the 4096 ROIs by Morton code of their center.
// Single block; produces perm[slot] = roi index. Any permutation is correct
// (main kernel scatters outputs by true roi index) — key quality only affects
// locality, never correctness.
// ---------------------------------------------------------------------------
__global__ __launch_bounds__(256) void roi_sort_kernel(
    const f32x4* __restrict__ rois4,
    int* __restrict__ perm)
{
    __shared__ int hist[256];
    __shared__ int base[256];
    const int t = threadIdx.x;

    hist[t] = 0;
    __syncthreads();

    int key[16];
    #pragma unroll
    for (int i = 0; i < 16; ++i) {
        const int roi = i * 256 + t;
        const f32x4 r = rois4[roi];
        const float cx = 0.5f * (r[0] + r[2]);
        const float cy = 0.5f * (r[1] + r[3]);
        int kx = (int)(cx * 16.0f);
        int ky = (int)(cy * 16.0f);
        kx = min(15, max(0, kx));
        ky = min(15, max(0, ky));
        int k = 0;
        #pragma unroll
        for (int b = 0; b < 4; ++b) {
            k |= ((kx >> b) & 1) << (2 * b + 1);
            k |= ((ky >> b) & 1) << (2 * b);
        }
        key[i] = k;
        atomicAdd(&hist[k], 1);
    }
    __syncthreads();

    if (t == 0) {                       // exclusive scan, 256 elems, trivial
        int acc = 0;
        for (int k = 0; k < 256; ++k) { base[k] = acc; acc += hist[k]; }
    }
    __syncthreads();

    #pragma unroll
    for (int i = 0; i < 16; ++i) {
        const int roi = i * 256 + t;
        const int pos = atomicAdd(&base[key[i]], 1);
        perm[pos] = roi;
    }
}

// ---------------------------------------------------------------------------
// Pass 2: R3 structure (plane-banded XCD mapping, compiler-scheduled loads)
// with ROI indirection through perm so each wave's 8 ROIs are spatial
// neighbors -> texel lines overlap within a wave and across waves (L1/L2).
// ---------------------------------------------------------------------------
__global__ __launch_bounds__(256) void psroi_align_kernel(
    const f32x4* __restrict__ feat,
    const f32x4* __restrict__ rois4,
    const int* __restrict__ perm,
    f32x4* __restrict__ out4)
{
    const int bid   = blockIdx.x;
    const int xcd   = bid & (NXCD - 1);
    const int j     = bid >> 3;
    const int s     = xcd * SLOTS_PER_XCD + j;   // contiguous slot band per XCD
    const int g     = s >> 7;                    // plane 0..48
    const int chunk = s & (CHUNKS_PER_PLANE - 1);
    const int tpl   = (chunk << 8) + threadIdx.x;
    const int c4    = tpl & (C4N - 1);
    const int slot  = tpl >> 3;                  // sorted slot
    const int roi   = perm[slot];                // true roi (8 lanes same addr)

    const f32x4 r = rois4[roi];            // [xmin, ymin, xmax, ymax]

    const float step_x = (r[2] - r[0]) * (1.0f / POOLK);
    const float step_y = (r[3] - r[1]) * (1.0f / POOLK);

    const int p = g / POOLK;               // x bin
    const int q = g % POOLK;               // y bin

    const float x1 = r[0] + (float)p * step_x;
    const float y1 = r[1] + (float)q * step_y;

    const float scale = (float)(HH - 1);   // 127
    float ys[2], xs[2];
    ys[0] = y1 * scale;
    ys[1] = (y1 + step_y) * scale;
    xs[0] = x1 * scale;
    xs[1] = (x1 + step_x) * scale;

    float wy[2], wx[2];
    bool  vy[2], vx[2];
    int   yrow[4], xcol[4];                // {lo(s0),hi(s0),lo(s1),hi(s1)}
    #pragma unroll
    for (int sa = 0; sa < 2; ++sa) {
        const float yg = ys[sa];
        vy[sa] = (yg >= 0.0f) && (yg <= (float)(HH - 1));
        const float y0f = floorf(yg);
        wy[sa] = yg - y0f;
        int y0 = min(max((int)y0f, 0), HH - 1);
        yrow[2 * sa]     = y0;
        yrow[2 * sa + 1] = min(y0 + 1, HH - 1);

        const float xg = xs[sa];
        vx[sa] = (xg >= 0.0f) && (xg <= (float)(WW - 1));
        const float x0f = floorf(xg);
        wx[sa] = xg - x0f;
        int x0 = min(max((int)x0f, 0), WW - 1);
        xcol[2 * sa]     = x0;
        xcol[2 * sa + 1] = min(x0 + 1, WW - 1);
    }

    const int gbase = g * C4N + c4;

    int rowoff[4], coloff[4];
    #pragma unroll
    for (int i = 0; i < 4; ++i) {
        rowoff[i] = yrow[i] * (WW * F4_PER_PIX) + gbase;
        coloff[i] = xcol[i] * F4_PER_PIX;
    }

    f32x4 ld[16];
    #pragma unroll
    for (int rr = 0; rr < 4; ++rr) {
        #pragma unroll
        for (int cc = 0; cc < 4; ++cc) {
            ld[rr * 4 + cc] = feat[rowoff[rr] + coloff[cc]];
        }
    }

    f32x4 vmax = { -INFINITY, -INFINITY, -INFINITY, -INFINITY };

    #pragma unroll
    for (int sy = 0; sy < 2; ++sy) {
        #pragma unroll
        for (int sx = 0; sx < 2; ++sx) {
            const float w11 = wy[sy] * wx[sx];
            const float w10 = wy[sy] - w11;            // wy*(1-wx)
            const float w01 = wx[sx] - w11;            // (1-wy)*wx
            const float w00 = 1.0f - wy[sy] - wx[sx] + w11;

            const f32x4 v00 = ld[(2 * sy)     * 4 + (2 * sx)];
            const f32x4 v01 = ld[(2 * sy)     * 4 + (2 * sx + 1)];
            const f32x4 v10 = ld[(2 * sy + 1) * 4 + (2 * sx)];
            const f32x4 v11 = ld[(2 * sy + 1) * 4 + (2 * sx + 1)];

            f32x4 v = v00 * w00 + v01 * w01 + v10 * w10 + v11 * w11;

            if (!(vy[sy] && vx[sx])) v = (f32x4){0.0f, 0.0f, 0.0f, 0.0f};

            #pragma unroll
            for (int jj = 0; jj < 4; ++jj) vmax[jj] = fmaxf(vmax[jj], v[jj]);
        }
    }

    // Scatter by TRUE roi index: (roi*49 + g)*8 + c4; 8 lanes write 128 B contig.
    out4[(roi * NBINS + g) * C4N + c4] = vmax;
}

extern "C" void kernel_launch(void* const* d_in, const int* in_sizes, int n_in,
                              void* d_out, int out_size, void* d_ws, size_t ws_size,
                              hipStream_t stream) {
    const f32x4* feat = (const f32x4*)d_in[0];
    const f32x4* rois = (const f32x4*)d_in[1];
    f32x4* out = (f32x4*)d_out;
    int* perm = (int*)d_ws;                     // 4096 ints = 16 KB scratch

    roi_sort_kernel<<<1, 256, 0, stream>>>(rois, perm);

    const int grid = NXCD * SLOTS_PER_XCD;      // 6272 blocks x 256 threads
    psroi_align_kernel<<<grid, 256, 0, stream>>>(feat, rois, perm, out);
}